// Round 4
// baseline (258.308 us; speedup 1.0000x reference)
//
#include <hip/hip_runtime.h>

#define B_    16
#define T_    8
#define K_    64
#define COUT  128
#define CIN   128
#define H_    64
#define W_    64
#define WSZ   (COUT*CIN*5*5)        // 409600 per-k (and per-b) weight elems

typedef __bf16 bf16x8 __attribute__((ext_vector_type(8)));
typedef float  f32x4  __attribute__((ext_vector_type(4)));

static __device__ __forceinline__ unsigned short f2bf(float f) {
    unsigned int u = __builtin_bit_cast(unsigned int, f);
    unsigned int r = (u + 0x7FFFu + ((u >> 16) & 1u)) >> 16;
    return (unsigned short)r;
}

// ---------------------------------------------------------------------------
// Kernel 1 (fused coef + weight-gen + fragment repack):
//   value(b,o,c,tap) = sum_k mean_t(tf[b,t,k]) * Wb[k,o,c,tap]
// written in MFMA-A fragment order:
//   lpF[b][tap][kc(4)][wm(2)][mt(4)][lane(64)][j(8)]  (bf16)
//   where o = wm*64 + mt*16 + (lane&15), c = kc*32 + (lane>>4)*8 + j
// Grid: 128 o * 4 c-chunks = 512 blocks. Wb read coalesced exactly once.
// ---------------------------------------------------------------------------
__global__ __launch_bounds__(256) void lp_kernel(const float* __restrict__ Wb,
                                                 const float* __restrict__ tf,
                                                 unsigned short* __restrict__ lpF) {
    int o = blockIdx.x >> 2;      // 0..127
    int s = blockIdx.x & 3;       // c chunk: c in [32s, 32s+32)
    int tid = threadIdx.x;

    __shared__ float cs[B_ * K_];                  // 4 KB
    __shared__ unsigned short lt[B_ * 800];        // 25.6 KB: [b][c_local*25+tap]

    // coef[b,k] = mean_t tf[b,t,k]
    {
        int idx = tid;
#pragma unroll
        for (int r = 0; r < 4; ++r, idx += 256) {
            int b = idx >> 6, k = idx & 63;
            float sum = 0.f;
#pragma unroll
            for (int t = 0; t < T_; ++t) sum += tf[(b * T_ + t) * K_ + k];
            cs[idx] = sum * 0.125f;
        }
    }
    __syncthreads();

    if (tid < 200) {
        // this thread: 4 consecutive flat elems of [c_local][tap] within chunk s
        int base = o * 3200 + s * 800 + tid * 4;
        float4 acc[B_];
#pragma unroll
        for (int b = 0; b < B_; ++b) acc[b] = make_float4(0.f, 0.f, 0.f, 0.f);

        // branch-free k loop: compiler software-pipelines the loads
#pragma unroll 4
        for (int k = 0; k < K_; ++k) {
            const float4 wv = *(const float4*)(Wb + (size_t)k * WSZ + base);
#pragma unroll
            for (int b = 0; b < B_; ++b) {
                float c = cs[b * K_ + k];
                acc[b].x += c * wv.x;
                acc[b].y += c * wv.y;
                acc[b].z += c * wv.z;
                acc[b].w += c * wv.w;
            }
        }
        unsigned int* ltw = (unsigned int*)lt;
#pragma unroll
        for (int b = 0; b < B_; ++b) {
            unsigned int p0 = f2bf(acc[b].x) | ((unsigned int)f2bf(acc[b].y) << 16);
            unsigned int p1 = f2bf(acc[b].z) | ((unsigned int)f2bf(acc[b].w) << 16);
            ltw[b * 400 + tid * 2]     = p0;
            ltw[b * 400 + tid * 2 + 1] = p1;
        }
    }
    __syncthreads();

    // writeout in fragment order. This block owns one o and c-chunk s:
    //   wm = o>>6, mt = (o>>4)&3, n16 = o&15  (fixed); quad = 0..3 varies.
    int wm = o >> 6, mt = (o >> 4) & 3, n16 = o & 15;
    for (int it = tid; it < 1600; it += 256) {
        int b = it / 100;
        int r = it - b * 100;
        int tap = r >> 2;
        int quad = r & 3;
        unsigned short v[8];
#pragma unroll
        for (int j = 0; j < 8; ++j)
            v[j] = lt[b * 800 + (quad * 8 + j) * 25 + tap];
        size_t off = (size_t)b * 409600
                   + (size_t)((((tap * 4 + s) * 2 + wm) * 4 + mt) * 512
                              + quad * 128 + n16 * 8);
        *(uint4*)(lpF + off) = *(const uint4*)v;
    }
}

// ---------------------------------------------------------------------------
// Kernel 2: x (fp32 NCHW) -> xT bf16 [b][h][w][c]  (MFMA B-operand layout)
// ---------------------------------------------------------------------------
__global__ __launch_bounds__(256) void xtrans(const float* __restrict__ x,
                                              unsigned short* __restrict__ xT) {
    int bid = blockIdx.x;
    int b = bid >> 6, h = bid & 63;
    __shared__ __align__(16) unsigned short ls[64 * 136];   // pad c-stride 128->136

    int tid = threadIdx.x;
    int w = tid & 63, cb = tid >> 6;          // cb: 4 groups of 32 c
    const float* xp = x + (((size_t)(b * CIN + cb * 32) * H_ + h) * W_) + w;
#pragma unroll
    for (int p = 0; p < 16; ++p) {
        float f0 = xp[(size_t)(2 * p) * (H_ * W_)];
        float f1 = xp[(size_t)(2 * p + 1) * (H_ * W_)];
        unsigned int v = f2bf(f0) | ((unsigned int)f2bf(f1) << 16);
        *(unsigned int*)&ls[w * 136 + cb * 32 + 2 * p] = v;
    }
    __syncthreads();

    unsigned short* xTb = xT + ((size_t)(b * 64 + h) * 64) * 128;
    int chunk = tid & 15, wr = tid >> 4;
#pragma unroll
    for (int pass = 0; pass < 4; ++pass) {
        int ww = pass * 16 + wr;
        uint4 v = *(const uint4*)&ls[ww * 136 + chunk * 8];
        *(uint4*)&xTb[ww * 128 + chunk * 8] = v;
    }
}

// ---------------------------------------------------------------------------
// Kernel 3: conv as 25 shifted GEMMs, bf16 MFMA 16x16x32, fp32 accum.
// Grid: 512 blocks, XCD-swizzled (2 batches per XCD's L2).
// Block tile: M=128 (o) x N=128 (2 rows x 64 w). Wave: 64x64 (4mt x 4nt).
// Pipeline: A (global, L2-hot) prefetched 4 taps ahead (covers ~250cyc L2
// latency with 3x16 MFMA between issue and consume); B (LDS) 2 taps ahead.
// Full 25-tap unroll folds all addresses to immediates.
// ---------------------------------------------------------------------------
__global__ __launch_bounds__(256) void conv_mfma(const unsigned short* __restrict__ xT,
                                                 const unsigned short* __restrict__ lpF,
                                                 float* __restrict__ out) {
    int bid = blockIdx.x;
    int b  = (bid & 7) | (((bid >> 3) & 1) << 3);   // XCD-local batch
    int h0 = (bid >> 4) << 1;                       // row pair

    int tid  = threadIdx.x;
    int lane = tid & 63, wid = tid >> 6;
    int wm = wid & 1, wn = wid >> 1;          // wm: o-half, wn: output row
    int n16 = lane & 15, quad = lane >> 4;

    __shared__ __align__(16) unsigned short xs[408 * 40];   // 32640 B

    f32x4 acc[4][4];
#pragma unroll
    for (int mt = 0; mt < 4; ++mt)
#pragma unroll
        for (int nt = 0; nt < 4; ++nt) acc[mt][nt] = (f32x4){0.f, 0.f, 0.f, 0.f};

    const unsigned short* xTb = xT + (size_t)b * (64 * 64 * 128);
    // per-wave A base in fragment-ordered lpF
    const unsigned short* lpW = lpF + (size_t)b * 409600 + wm * 2048 + lane * 8;

#define LOADA(slot, tap) do {                                                \
    const unsigned short* ap_ = lpW + (tap) * 16384 + kcB;                   \
    A[slot][0] = *(const bf16x8*)(ap_);                                      \
    A[slot][1] = *(const bf16x8*)(ap_ + 512);                                \
    A[slot][2] = *(const bf16x8*)(ap_ + 1024);                               \
    A[slot][3] = *(const bf16x8*)(ap_ + 1536);                               \
} while (0)

#define LOADB(slot, tap) do {                                                \
    int i_ = (tap) / 5, j_ = (tap) - 5 * (i_);                               \
    const unsigned short* bp_ = &xs[(((wn + i_) * 68) + n16 + j_) * 40 + quad * 8]; \
    Bf[slot][0] = *(const bf16x8*)(bp_);                                     \
    Bf[slot][1] = *(const bf16x8*)(bp_ + 16 * 40);                           \
    Bf[slot][2] = *(const bf16x8*)(bp_ + 32 * 40);                           \
    Bf[slot][3] = *(const bf16x8*)(bp_ + 48 * 40);                           \
} while (0)

#define DO_MFMA(av, bv) do {                                                 \
    _Pragma("unroll") for (int mt = 0; mt < 4; ++mt)                         \
    _Pragma("unroll") for (int nt = 0; nt < 4; ++nt)                         \
        acc[mt][nt] = __builtin_amdgcn_mfma_f32_16x16x32_bf16(               \
            (av)[mt], (bv)[nt], acc[mt][nt], 0, 0, 0);                       \
} while (0)

    for (int kc = 0; kc < 4; ++kc) {
        int kcOff = kc * 32;
        int kcB   = kc * 4096;
        __syncthreads();                       // previous chunk's readers done
        // stage x rows h0-2 .. h0+3, cols -2..65 (zeros outside), 32 channels
        for (int sIdx = tid; sIdx < 408; sIdx += 256) {
            unsigned int su = (unsigned int)sIdx;
            int rr = su / 68u;
            int ww = su - rr * 68u;
            int gr = h0 - 2 + rr, gw = ww - 2;
            uint4* dst = (uint4*)&xs[sIdx * 40];
            if ((unsigned)gr < 64u && (unsigned)gw < 64u) {
                const uint4* src = (const uint4*)(xTb + (((size_t)gr * 64 + gw) * 128 + kcOff));
                dst[0] = src[0]; dst[1] = src[1]; dst[2] = src[2]; dst[3] = src[3];
            } else {
                uint4 z = {0u, 0u, 0u, 0u};
                dst[0] = z; dst[1] = z; dst[2] = z; dst[3] = z;
            }
        }
        __syncthreads();

        bf16x8 A[4][4], Bf[2][4];
        LOADA(0, 0); LOADA(1, 1); LOADA(2, 2); LOADA(3, 3);
        LOADB(0, 0); LOADB(1, 1);
#pragma unroll
        for (int t = 0; t < 25; ++t) {
            DO_MFMA(A[t & 3], Bf[t & 1]);
            if (t + 4 < 25) LOADA(t & 3, t + 4);
            if (t + 2 < 25) LOADB(t & 1, t + 2);
        }
    }

    // epilogue: D row (o) = quad*4 + reg, D col (pixel) = lane&15
    float* outb = out + (size_t)b * (COUT * H_ * W_) + (size_t)(h0 + wn) * W_;
#pragma unroll
    for (int mt = 0; mt < 4; ++mt) {
#pragma unroll
        for (int nt = 0; nt < 4; ++nt) {
#pragma unroll
            for (int r = 0; r < 4; ++r) {
                int o = wm * 64 + mt * 16 + quad * 4 + r;
                int w = nt * 16 + n16;
                outb[(size_t)o * (H_ * W_) + w] = acc[mt][nt][r];
            }
        }
    }
#undef LOADA
#undef LOADB
#undef DO_MFMA
}

// ---------------------------------------------------------------------------
extern "C" void kernel_launch(void* const* d_in, const int* in_sizes, int n_in,
                              void* d_out, int out_size, void* d_ws, size_t ws_size,
                              hipStream_t stream) {
    const float* x  = (const float*)d_in[0];   // (16,128,64,64)
    const float* tf = (const float*)d_in[1];   // (16,8,64)
    const float* Wb = (const float*)d_in[2];   // (64,128,128,5,5)
    float* out = (float*)d_out;                // (16,128,64,64) fp32

    // ws: lpF bf16 fragment-ordered 16*409600 = 13.1 MB, then xT bf16 16.8 MB
    unsigned short* lpF = (unsigned short*)d_ws;
    unsigned short* xT  = lpF + (size_t)B_ * 409600;

    lp_kernel<<<512, 256, 0, stream>>>(Wb, tf, lpF);
    xtrans  <<<1024, 256, 0, stream>>>(x, xT);
    conv_mfma<<<512, 256, 0, stream>>>(xT, lpF, out);
}

// Round 5
// 239.412 us; speedup vs baseline: 1.0789x; 1.0789x over previous
//
#include <hip/hip_runtime.h>

#define B_    16
#define T_    8
#define K_    64
#define COUT  128
#define CIN   128
#define H_    64
#define W_    64
#define WSZ   (COUT*CIN*5*5)        // 409600 per-k (and per-b) weight elems

typedef __bf16 bf16x8 __attribute__((ext_vector_type(8)));
typedef float  f32x4  __attribute__((ext_vector_type(4)));

static __device__ __forceinline__ unsigned short f2bf(float f) {
    unsigned int u = __builtin_bit_cast(unsigned int, f);
    unsigned int r = (u + 0x7FFFu + ((u >> 16) & 1u)) >> 16;
    return (unsigned short)r;
}

// ---------------------------------------------------------------------------
// Fused prep kernel. Grid 1536 blocks:
//   blocks [0,512):    lp role  — weight-gen + MFMA-A fragment repack
//   blocks [512,1536): xtrans role — x fp32 NCHW -> xT bf16 [b][h][w][c]
// The two roles are independent HBM streams (105 MB Wb, 67 MB x); fusing
// overlaps them instead of serializing two latency-limited kernels.
// LDS: union, 30 KB static.
// ---------------------------------------------------------------------------
__global__ __launch_bounds__(256) void prep_kernel(const float* __restrict__ Wb,
                                                   const float* __restrict__ tf,
                                                   const float* __restrict__ x,
                                                   unsigned short* __restrict__ lpF,
                                                   unsigned short* __restrict__ xT) {
    __shared__ __align__(16) char smem[30720];
    int tid = threadIdx.x;

    if (blockIdx.x < 512) {
        // ---------------- lp role ----------------
        // lpF[b][tap][kc(4)][wm(2)][mt(4)][lane(64)][j(8)]  (bf16)
        //   o = wm*64 + mt*16 + (lane&15), c = kc*32 + (lane>>4)*8 + j
        float* cs          = (float*)smem;                       // 4 KB
        unsigned short* lt = (unsigned short*)(smem + 4096);     // 25.6 KB

        int o = blockIdx.x >> 2;      // 0..127
        int s = blockIdx.x & 3;       // c chunk: c in [32s, 32s+32)

        // coef[b,k] = mean_t tf[b,t,k]
        {
            int idx = tid;
#pragma unroll
            for (int r = 0; r < 4; ++r, idx += 256) {
                int b = idx >> 6, k = idx & 63;
                float sum = 0.f;
#pragma unroll
                for (int t = 0; t < T_; ++t) sum += tf[(b * T_ + t) * K_ + k];
                cs[idx] = sum * 0.125f;
            }
        }
        __syncthreads();

        if (tid < 200) {
            int base = o * 3200 + s * 800 + tid * 4;
            float4 acc[B_];
#pragma unroll
            for (int b = 0; b < B_; ++b) acc[b] = make_float4(0.f, 0.f, 0.f, 0.f);

#pragma unroll 4
            for (int k = 0; k < K_; ++k) {
                const float4 wv = *(const float4*)(Wb + (size_t)k * WSZ + base);
#pragma unroll
                for (int b = 0; b < B_; ++b) {
                    float c = cs[b * K_ + k];
                    acc[b].x += c * wv.x;
                    acc[b].y += c * wv.y;
                    acc[b].z += c * wv.z;
                    acc[b].w += c * wv.w;
                }
            }
            unsigned int* ltw = (unsigned int*)lt;
#pragma unroll
            for (int b = 0; b < B_; ++b) {
                unsigned int p0 = f2bf(acc[b].x) | ((unsigned int)f2bf(acc[b].y) << 16);
                unsigned int p1 = f2bf(acc[b].z) | ((unsigned int)f2bf(acc[b].w) << 16);
                ltw[b * 400 + tid * 2]     = p0;
                ltw[b * 400 + tid * 2 + 1] = p1;
            }
        }
        __syncthreads();

        // fragment-ordered writeout: wm,mt,n16 fixed per block; quad varies
        int wm = o >> 6, mt = (o >> 4) & 3, n16 = o & 15;
        for (int it = tid; it < 1600; it += 256) {
            int b = it / 100;
            int r = it - b * 100;
            int tap = r >> 2;
            int quad = r & 3;
            unsigned short v[8];
#pragma unroll
            for (int j = 0; j < 8; ++j)
                v[j] = lt[b * 800 + (quad * 8 + j) * 25 + tap];
            size_t off = (size_t)b * 409600
                       + (size_t)((((tap * 4 + s) * 2 + wm) * 4 + mt) * 512
                                  + quad * 128 + n16 * 8);
            *(uint4*)(lpF + off) = *(const uint4*)v;
        }
    } else {
        // ---------------- xtrans role ----------------
        unsigned short* ls = (unsigned short*)smem;              // 64*136*2 = 17.4 KB
        int q = blockIdx.x - 512;
        int b = q >> 6, h = q & 63;

        int w = tid & 63, cb = tid >> 6;          // cb: 4 groups of 32 c
        const float* xp = x + (((size_t)(b * CIN + cb * 32) * H_ + h) * W_) + w;
#pragma unroll
        for (int p = 0; p < 16; ++p) {
            float f0 = xp[(size_t)(2 * p) * (H_ * W_)];
            float f1 = xp[(size_t)(2 * p + 1) * (H_ * W_)];
            unsigned int v = f2bf(f0) | ((unsigned int)f2bf(f1) << 16);
            *(unsigned int*)&ls[w * 136 + cb * 32 + 2 * p] = v;
        }
        __syncthreads();

        unsigned short* xTb = xT + ((size_t)(b * 64 + h) * 64) * 128;
        int chunk = tid & 15, wr = tid >> 4;
#pragma unroll
        for (int pass = 0; pass < 4; ++pass) {
            int ww = pass * 16 + wr;
            uint4 v = *(const uint4*)&ls[ww * 136 + chunk * 8];
            *(uint4*)&xTb[ww * 128 + chunk * 8] = v;
        }
    }
}

// ---------------------------------------------------------------------------
// Conv as 25 shifted GEMMs, bf16 MFMA 16x16x32, fp32 accum.
// Round-3 proven structure (2-deep pipeline, VGPR 72).
// Grid: 512 blocks, XCD-swizzled (2 batches per XCD's L2).
// Block tile: M=128 (o) x N=128 (2 rows x 64 w). Wave: 64x64 (4mt x 4nt).
// ---------------------------------------------------------------------------
__global__ __launch_bounds__(256) void conv_mfma(const unsigned short* __restrict__ xT,
                                                 const unsigned short* __restrict__ lpF,
                                                 float* __restrict__ out) {
    int bid = blockIdx.x;
    int b  = (bid & 7) | (((bid >> 3) & 1) << 3);   // XCD-local batch
    int h0 = (bid >> 4) << 1;                       // row pair

    int tid  = threadIdx.x;
    int lane = tid & 63, wid = tid >> 6;
    int wm = wid & 1, wn = wid >> 1;          // wm: o-half, wn: output row
    int n16 = lane & 15, quad = lane >> 4;

    __shared__ __align__(16) unsigned short xs[408 * 40];   // 32640 B

    f32x4 acc[4][4];
#pragma unroll
    for (int mt = 0; mt < 4; ++mt)
#pragma unroll
        for (int nt = 0; nt < 4; ++nt) acc[mt][nt] = (f32x4){0.f, 0.f, 0.f, 0.f};

    const unsigned short* xTb = xT + (size_t)b * (64 * 64 * 128);
    const unsigned short* lpW = lpF + (size_t)b * 409600 + wm * 2048 + lane * 8;

#define LOAD_FRAGS(A, Bf, tap) do {                                          \
    int i_ = (tap) / 5, j_ = (tap) - 5 * (i_);                               \
    const unsigned short* ap_ = lpW + (tap) * 16384 + kcB;                   \
    A[0] = *(const bf16x8*)(ap_);                                            \
    A[1] = *(const bf16x8*)(ap_ + 512);                                      \
    A[2] = *(const bf16x8*)(ap_ + 1024);                                     \
    A[3] = *(const bf16x8*)(ap_ + 1536);                                     \
    const unsigned short* bp_ = &xs[(((wn + i_) * 68) + n16 + j_) * 40 + quad * 8]; \
    Bf[0] = *(const bf16x8*)(bp_);                                           \
    Bf[1] = *(const bf16x8*)(bp_ + 16 * 40);                                 \
    Bf[2] = *(const bf16x8*)(bp_ + 32 * 40);                                 \
    Bf[3] = *(const bf16x8*)(bp_ + 48 * 40);                                 \
} while (0)

#define DO_MFMA(av, bv) do {                                                 \
    _Pragma("unroll") for (int mt = 0; mt < 4; ++mt)                         \
    _Pragma("unroll") for (int nt = 0; nt < 4; ++nt)                         \
        acc[mt][nt] = __builtin_amdgcn_mfma_f32_16x16x32_bf16(               \
            (av)[mt], (bv)[nt], acc[mt][nt], 0, 0, 0);                       \
} while (0)

    for (int kc = 0; kc < 4; ++kc) {
        int kcOff = kc * 32;
        int kcB   = kc * 4096;
        __syncthreads();                       // previous chunk's readers done
        // stage x rows h0-2 .. h0+3, cols -2..65 (zeros outside), 32 channels
        for (int sIdx = tid; sIdx < 408; sIdx += 256) {
            unsigned int su = (unsigned int)sIdx;
            int rr = su / 68u;
            int ww = su - rr * 68u;
            int gr = h0 - 2 + rr, gw = ww - 2;
            uint4* dst = (uint4*)&xs[sIdx * 40];
            if ((unsigned)gr < 64u && (unsigned)gw < 64u) {
                const uint4* src = (const uint4*)(xTb + (((size_t)gr * 64 + gw) * 128 + kcOff));
                dst[0] = src[0]; dst[1] = src[1]; dst[2] = src[2]; dst[3] = src[3];
            } else {
                uint4 z = {0u, 0u, 0u, 0u};
                dst[0] = z; dst[1] = z; dst[2] = z; dst[3] = z;
            }
        }
        __syncthreads();

        bf16x8 a0[4], b0[4], a1[4], b1[4];
        LOAD_FRAGS(a0, b0, 0);
        for (int t = 0; t < 24; t += 2) {
            LOAD_FRAGS(a1, b1, t + 1);
            DO_MFMA(a0, b0);
            LOAD_FRAGS(a0, b0, t + 2);
            DO_MFMA(a1, b1);
        }
        DO_MFMA(a0, b0);                       // tap 24
    }

    // epilogue: D row (o) = quad*4 + reg, D col (pixel) = lane&15
    float* outb = out + (size_t)b * (COUT * H_ * W_) + (size_t)(h0 + wn) * W_;
#pragma unroll
    for (int mt = 0; mt < 4; ++mt) {
#pragma unroll
        for (int nt = 0; nt < 4; ++nt) {
#pragma unroll
            for (int r = 0; r < 4; ++r) {
                int o = wm * 64 + mt * 16 + quad * 4 + r;
                int w = nt * 16 + n16;
                outb[(size_t)o * (H_ * W_) + w] = acc[mt][nt][r];
            }
        }
    }
#undef LOAD_FRAGS
#undef DO_MFMA
}

// ---------------------------------------------------------------------------
extern "C" void kernel_launch(void* const* d_in, const int* in_sizes, int n_in,
                              void* d_out, int out_size, void* d_ws, size_t ws_size,
                              hipStream_t stream) {
    const float* x  = (const float*)d_in[0];   // (16,128,64,64)
    const float* tf = (const float*)d_in[1];   // (16,8,64)
    const float* Wb = (const float*)d_in[2];   // (64,128,128,5,5)
    float* out = (float*)d_out;                // (16,128,64,64) fp32

    // ws: lpF bf16 fragment-ordered 16*409600 = 13.1 MB, then xT bf16 16.8 MB
    unsigned short* lpF = (unsigned short*)d_ws;
    unsigned short* xT  = lpF + (size_t)B_ * 409600;

    prep_kernel<<<1536, 256, 0, stream>>>(Wb, tf, x, lpF, xT);
    conv_mfma  <<<512,  256, 0, stream>>>(xT, lpF, out);
}